// Round 7
// baseline (192.728 us; speedup 1.0000x reference)
//
#include <hip/hip_runtime.h>
#include <hip/hip_bf16.h>

// HaloNet-style windowed attention, MI355X gfx950.  f32 in / f32 out.
// bf16 MFMA internals; w hi/lo split keeps conv weights exact; x/q/k/v/P/ao
// single bf16 (absmax ~4.9e-4 vs 2.54e-3 threshold).
// ws layout (shorts):
//   q_t [head][pix][16]                    12,582,912   (scaled 0.25*log2e)
//   k_t [head*2+b][260*260 padded][16]     12,979,200   (2-px ZERO border)
//   v_t [head][pix][16]                    12,582,912
//   ao  [head][pix][16]                    12,582,912
//   weights/tables/sbias                       ~75,616
// Total ~101.6 MB.
//
// This round: qkv/proj occupancy via OUTPUT-CHANNEL SPLIT (round-6's px
// re-index NaN'd -> reverted).  Grid (512,2): blockIdx.y picks t6 range
// [9y,9y+9) (qkv) / mt range [3y,3y+3) (proj).  Pixel indexing is byte-
// identical to the round-5 verified code; y-blocks write disjoint channel
// ranges.  2 -> 4 blocks/CU (4 waves/SIMD) hides load latency; cost is a
// 2x re-read of x (+50 MB) and ao (+25 MB), hidden by the doubled TLP.
// attn unchanged (53.6 us, occ 71%, permlane in-register P transpose).

typedef __attribute__((ext_vector_type(8))) short bf16x8;
typedef __attribute__((ext_vector_type(4))) float f32x4;
typedef __attribute__((ext_vector_type(4))) unsigned u32x4;

__device__ __forceinline__ f32x4 mfma16(bf16x8 a, bf16x8 b, f32x4 c) {
  // D[a_idx][b_idx] = sum_k A[a_idx][k]*B[b_idx][k]
  // A/B frag: idx=lane&15, k=(lane>>4)*8+j; D: col=lane&15 (B-idx),
  // row=(lane>>4)*4+reg (A-idx)   [learn_hip m89/m91]
  return __builtin_amdgcn_mfma_f32_16x16x32_bf16(a, b, c, 0, 0, 0);
}
// branchless RNE f32->bf16 (finite inputs only — true for this problem)
__device__ __forceinline__ short f2b(float f) {
  unsigned u = __builtin_bit_cast(unsigned, f);
  unsigned r = u + 0x7fffu + ((u >> 16) & 1u);
  return (short)(r >> 16);
}
// packed RNE pair: low16 = bf16(lo), high16 = bf16(hi)
__device__ __forceinline__ unsigned cvtpk(float lo, float hi) {
  unsigned r;
  asm("v_cvt_pk_bf16_f32 %0, %1, %2" : "=v"(r) : "v"(lo), "v"(hi));
  return r;
}
// a' = [a.r0, b.r0, a.r2, b.r2], b' = [a.r1, b.r1, a.r3, b.r3]  (r = 16-lane row)
__device__ __forceinline__ void pl16s(unsigned& a, unsigned& b) {
  asm("v_permlane16_swap_b32 %0, %1" : "+v"(a), "+v"(b));
}
// a' = [a.lo32, b.lo32], b' = [a.hi32, b.hi32]
__device__ __forceinline__ void pl32s(unsigned& a, unsigned& b) {
  asm("v_permlane32_swap_b32 %0, %1" : "+v"(a), "+v"(b));
}
// x = hi + lo, hi = trunc-to-bf16(x) (x-hi exact), lo = RNE(residual)
__device__ __forceinline__ void splitf(float x, short& h, short& l) {
  unsigned u = __builtin_bit_cast(unsigned, x);
  h = (short)(u >> 16);
  float fh = __builtin_bit_cast(float, u & 0xffff0000u);
  l = f2b(x - fh);
}

#define KPLANE 1081600L  // 67600 px * 16 ch
#define QS (0.25f * 1.44269504f)

// ---------------------------------------------------------------------------
// Kernel 0: one-time prep — split conv weights hi/lo (q rows pre-scaled by
// 0.25*log2e), scaled bias, rel tables, zero the 2-px border of all 12
// padded K planes.  Grid 108x256 = 27648 threads covers all tasks.
// ---------------------------------------------------------------------------
__global__ __launch_bounds__(256) void prep_kernel(
    const float* __restrict__ qkv_w, const float* __restrict__ proj_w,
    const float* __restrict__ rel_h, const float* __restrict__ rel_w,
    const float* __restrict__ qkv_b,
    short* __restrict__ qwh, short* __restrict__ qwl,
    short* __restrict__ pwh, short* __restrict__ pwl,
    short* __restrict__ rhb, short* __restrict__ rwb,
    float* __restrict__ sbias, short* __restrict__ k_t) {
  int i = blockIdx.x * 256 + threadIdx.x;
  if (i < 288 * 96) {
    float wv = qkv_w[i];
    if (i < 96 * 96) wv *= QS;  // q rows pre-scaled
    short h, l;
    splitf(wv, h, l);
    qwh[i] = h;
    qwl[i] = l;
  }
  if (i < 96 * 96) {
    short h, l;
    splitf(proj_w[i], h, l);
    pwh[i] = h;
    pwl[i] = l;
  }
  if (i < 368) {
    rhb[i] = f2b(rel_h[i]);
    rwb[i] = f2b(rel_w[i]);
  }
  if (i < 288) sbias[i] = qkv_b[i] * (i < 96 ? QS : 1.0f);
  if (i < 12 * 2064) {  // border pixels: rows {0,1,258,259} + cols {0,1,258,259}
    int plane = i / 2064, r = i - plane * 2064;
    int py, px;
    if (r < 1040) {
      int rowid = r / 260;
      py = (rowid < 2) ? rowid : 256 + rowid;
      px = r - rowid * 260;
    } else {
      int r2 = r - 1040;
      py = 2 + (r2 >> 2);
      int cid = r2 & 3;
      px = (cid < 2) ? cid : 256 + cid;
    }
    bf16x8 z = {0, 0, 0, 0, 0, 0, 0, 0};
    long base = (long)plane * KPLANE + (long)(py * 260 + px) * 16;
    *(bf16x8*)(k_t + base) = z;
    *(bf16x8*)(k_t + base + 8) = z;
  }
}

// ---------------------------------------------------------------------------
// Kernel 1: QKV 1x1 conv.  LDS-free.  Grid (512, 2) x 4 waves; wave = 64 px;
// blockIdx.y selects t6 range [9y, 9y+9) (disjoint output channels).
// B-frag (pixels) direct from planar f32: lane reads
// x[ks*32+quad*8+j][px0+col] (8 scalar dwords -> cvt_pk pack).  A = pre-
// split weights, prefetched one t6 ahead.  C row = output channel, col =
// pixel -> epilogue: 2 cvt_pk + 2 dword stores per tile.
// ---------------------------------------------------------------------------
__global__ __launch_bounds__(256) void qkv_kernel(
    const float* __restrict__ x, const short* __restrict__ qwh,
    const short* __restrict__ qwl, const float* __restrict__ sbias,
    short* __restrict__ q_t, short* __restrict__ k_t,
    short* __restrict__ v_t) {
  const int tid = threadIdx.x;
  const int wave = tid >> 6, lane = tid & 63;
  const int quad = lane >> 4, col = lane & 15;
  const int blk = blockIdx.x;        // 512 blocks = 2 images x 256 rows
  const int b = blk >> 8, row = blk & 255;
  const int t0 = blockIdx.y * 9;     // this block's t6 range: [t0, t0+9)

  // ---- B fragments: x[ch][pix] -> bf16, pixel=col, k=quad*8+j
  const float* xw = x + (((long)b * 96) << 16) + row * 256 + wave * 64 + col;
  bf16x8 bx[4][3];
#pragma unroll
  for (int tile = 0; tile < 4; ++tile)
#pragma unroll
    for (int ks = 0; ks < 3; ++ks) {
      const float* p = xw + tile * 16 + (((long)(ks * 32 + quad * 8)) << 16);
      float v0 = p[0];
      float v1 = p[1L << 16];
      float v2 = p[2L << 16];
      float v3 = p[3L << 16];
      float v4 = p[4L << 16];
      float v5 = p[5L << 16];
      float v6 = p[6L << 16];
      float v7 = p[7L << 16];
      union { unsigned u[4]; bf16x8 w; } t;
      t.u[0] = cvtpk(v0, v1);
      t.u[1] = cvtpk(v2, v3);
      t.u[2] = cvtpk(v4, v5);
      t.u[3] = cvtpk(v6, v7);
      bx[tile][ks] = t.w;
    }

  // ---- weight fragments (A): row = output = base+col
  const short* wbh = qwh + col * 96 + quad * 8;
  const short* wbl = qwl + col * 96 + quad * 8;
  bf16x8 wh[3], wl[3];
#pragma unroll
  for (int ks = 0; ks < 3; ++ks) {
    wh[ks] = *(const bf16x8*)(wbh + t0 * 1536 + ks * 32);
    wl[ks] = *(const bf16x8*)(wbl + t0 * 1536 + ks * 32);
  }

  const long pixb = (long)blk * 256 + wave * 64 + col;  // tile0 pixel
  short* kbase = k_t + (long)b * KPLANE +
                 ((long)((row + 2) * 260 + wave * 64 + col + 2)) * 16 +
                 quad * 4;

#pragma unroll
  for (int tt = 0; tt < 9; ++tt) {
    const int t6 = t0 + tt;
    bf16x8 nh[3], nl[3];
    if (tt < 8) {
#pragma unroll
      for (int ks = 0; ks < 3; ++ks) {
        nh[ks] = *(const bf16x8*)(wbh + (t6 + 1) * 1536 + ks * 32);
        nl[ks] = *(const bf16x8*)(wbl + (t6 + 1) * 1536 + ks * 32);
      }
    }
    f32x4 bv = *(const f32x4*)(sbias + t6 * 16 + quad * 4);
    f32x4 acc[4] = {bv, bv, bv, bv};
#pragma unroll
    for (int ks = 0; ks < 3; ++ks)
#pragma unroll
      for (int tile = 0; tile < 4; ++tile) {
        acc[tile] = mfma16(wh[ks], bx[tile][ks], acc[tile]);
        acc[tile] = mfma16(wl[ks], bx[tile][ks], acc[tile]);
      }
#pragma unroll
    for (int tile = 0; tile < 4; ++tile) {
      unsigned d0 = cvtpk(acc[tile][0], acc[tile][1]);  // ch quad*4+0,1
      unsigned d1 = cvtpk(acc[tile][2], acc[tile][3]);  // ch quad*4+2,3
      if (t6 >= 6 && t6 < 12) {  // k: padded planes [head*2+b]
        short* kp = kbase + (long)(t6 - 6) * (2 * KPLANE) + tile * 256;
        *(unsigned*)kp = d0;
        *(unsigned*)(kp + 2) = d1;
      } else {  // q/v: head-major [head][pix][16]
        short* plane = (t6 < 6 ? q_t : v_t) +
                       (long)(t6 < 6 ? t6 : t6 - 12) * 2097152 + pixb * 16 +
                       tile * 256 + quad * 4;
        *(unsigned*)plane = d0;
        *(unsigned*)(plane + 2) = d1;
      }
    }
    if (tt < 8) {
#pragma unroll
      for (int ks = 0; ks < 3; ++ks) {
        wh[ks] = nh[ks];
        wl[ks] = nl[ks];
      }
    }
  }
}

// ---------------------------------------------------------------------------
// Kernel 2: windowed attention.  One block per (window, head); 4 waves = 4
// query tiles; one barrier (V staging).  SWAPPED QK^T: L = mfma(kf, qf)
// -> query in lanes (col), keys in regs (kw = quad*4+r4, kh = nt).
// Key space 192 = 12 kh x 16 kw (kw 12-15 junk).  After exp2+cvt_pk the
// pair-dwords are transposed IN REGISTERS to the PV A-frag layout with 6
// permlane swaps per 32-key tile; P never touches LDS.  Softmax denom via
// ones-MFMA; rcp divide.  OOB keys: K=0 -> logit=bias; V slots zeroed ->
// numerator 0; exp(bias) in denominator == ref.
// ---------------------------------------------------------------------------
__global__ __launch_bounds__(256, 8) void attn_kernel(
    const short* __restrict__ q_t, const short* __restrict__ k_t,
    const short* __restrict__ v_t, const short* __restrict__ rhb,
    const short* __restrict__ rwb, short* __restrict__ ao) {
  __shared__ __attribute__((aligned(16))) short v_lds[16][210];
  __shared__ __attribute__((aligned(16))) float Wt[4][16][20];
  __shared__ __attribute__((aligned(16))) float Htab[4][16][20];

  const int orig = blockIdx.x, head = blockIdx.y;
  const int win = ((orig & 7) << 8) | (orig >> 3);  // XCD-chunked swizzle
  const int b = win >> 10, wy = (win & 1023) >> 5, wx = win & 31;
  const int y0 = wy * 8 - 2, x0 = wx * 8 - 2;
  const long pb = (long)b << 16;
  const int tid = threadIdx.x;

  // stage V transposed: v_lds[dh][slot], slot = kh*16+kw (192 slots);
  // OOB + junk kw (12-15) zeroed.
  if (tid < 192) {
    const int kh = tid >> 4, kw = tid & 15;
    const int gy = y0 + kh, gx = x0 + kw;
    const bool valid =
        (kw < 12) && ((unsigned)gy < 256u) && ((unsigned)gx < 256u);
    if (valid) {
      const short* src =
          v_t + (long)head * 2097152 + (pb + gy * 256 + gx) * 16;
      union { bf16x8 v; short s[8]; } u0, u1;
      u0.v = *(const bf16x8*)src;
      u1.v = *(const bf16x8*)(src + 8);
      for (int d = 0; d < 8; ++d) {
        v_lds[d][tid] = u0.s[d];
        v_lds[d + 8][tid] = u1.s[d];
      }
    } else {
      for (int d = 0; d < 16; ++d) v_lds[d][tid] = 0;
    }
  }
  __syncthreads();

  const int wave = tid >> 6, lane = tid & 63;
  const int quad = lane >> 4, col = lane & 15;
  float* Ws = &Wt[wave][0][0];    // [16][20]: Wbias[q][kw]
  float* Ht = &Htab[wave][0][0];  // [16][20]: Hbias[q][kh]

  const short* qp = q_t + (long)head * 2097152;
  const short* kpb = k_t + (long)(head * 2 + b) * KPLANE;

  // Q fragment (B operand: idx=col=query; K padded 16->32: quads 2,3 zero)
  bf16x8 qf = {0, 0, 0, 0, 0, 0, 0, 0};
  if (quad < 2) {
    int qg = wave * 16 + col;
    int qy = qg >> 3, qx = qg & 7;
    qf = *(const bf16x8*)(qp + (pb + (wy * 8 + qy) * 256 + wx * 8 + qx) * 16 +
                          quad * 8);
  }

  // rel-pos dot tables, stored pre-shifted: Ws[q][kw] = wdot[q][kw-qx+11],
  // Ht[q][kh] = hdot[q][kh-qy+11].  Producer lane (col=r, quad) reg r4
  // holds dot(q=quad*4+r4, rel[r]).
  for (int nt2 = 0; nt2 < 2; ++nt2) {
    int r = nt2 * 16 + col;
    bf16x8 bw = {0, 0, 0, 0, 0, 0, 0, 0}, bh2 = bw;
    if (quad < 2 && r < 23) {
      bw = *(const bf16x8*)(rwb + r * 16 + quad * 8);
      bh2 = *(const bf16x8*)(rhb + r * 16 + quad * 8);
    }
    f32x4 z = {0.f, 0.f, 0.f, 0.f};
    f32x4 aw = mfma16(qf, bw, z);
    f32x4 ahh = mfma16(qf, bh2, z);
    int kh = r - 11 + wave * 2 + (quad >> 1);  // r4-invariant (qy = q>>3)
#pragma unroll
    for (int r4 = 0; r4 < 4; ++r4) {
      int q = quad * 4 + r4;
      int kw = r - 11 + (q & 7);
      if ((unsigned)kw < 12u) Ws[q * 20 + kw] = aw[r4];
      if ((unsigned)kh < 12u) Ht[q * 20 + kh] = ahh[r4];
    }
  }
  asm volatile("" ::: "memory");

  // preload biases for q=col (read once; tables dead afterwards).
  // quad 3 reads Ws slots 12-15 (uninit junk) — its P is zeroed below.
  const f32x4 wv4 = *(const f32x4*)&Ws[col * 20 + quad * 4];  // kw=quad*4+r4
  const f32x4 h0 = *(const f32x4*)&Ht[col * 20];
  const f32x4 h1 = *(const f32x4*)&Ht[col * 20 + 4];
  const f32x4 h2 = *(const f32x4*)&Ht[col * 20 + 8];

  // QK^T (swapped) + bias-in-C + exp2 + in-register transpose + PV.
  // Tile pair (nt0=2ks, nt1=2ks+1): kh=nt, kw=quad*4+r4 in regs.
  const short* kb =
      kpb + (long)((wy * 8) * 260 + wx * 8 + col) * 16 + quad * 8;
  const bf16x8 ones = {0x3F80, 0x3F80, 0x3F80, 0x3F80,
                       0x3F80, 0x3F80, 0x3F80, 0x3F80};
  f32x4 oacc = {0.f, 0.f, 0.f, 0.f}, oaccS = oacc;
#pragma unroll
  for (int ks = 0; ks < 6; ++ks) {
    const int nt0 = 2 * ks, nt1 = 2 * ks + 1;
    bf16x8 kf0 = *(const bf16x8*)(kb + (long)nt0 * 4160);
    bf16x8 kf1 = *(const bf16x8*)(kb + (long)nt1 * 4160);
    float hs0 = nt0 < 4 ? h0[nt0] : (nt0 < 8 ? h1[nt0 - 4] : h2[nt0 - 8]);
    float hs1 = nt1 < 4 ? h0[nt1] : (nt1 < 8 ? h1[nt1 - 4] : h2[nt1 - 8]);
    f32x4 a0 = wv4 + hs0, a1 = wv4 + hs1;
    f32x4 L0 = mfma16(kf0, qf, a0);  // row=kw=quad*4+r4, col=q
    f32x4 L1 = mfma16(kf1, qf, a1);
    // pair-dwords: X=(kw 4quad,4quad+1), Y=(kw 4quad+2,+3) per nt
    unsigned X = cvtpk(__builtin_amdgcn_exp2f(L0[0]),
                       __builtin_amdgcn_exp2f(L0[1]));
    unsigned Y = cvtpk(__builtin_amdgcn_exp2f(L0[2]),
                       __builtin_amdgcn_exp2f(L0[3]));
    unsigned Xp = cvtpk(__builtin_amdgcn_exp2f(L1[0]),
                        __builtin_amdgcn_exp2f(L1[1]));
    unsigned Yp = cvtpk(__builtin_amdgcn_exp2f(L1[2]),
                        __builtin_amdgcn_exp2f(L1[3]));
    // 3-step swap network -> PV A-frag dwords (within q's lane-group):
    pl16s(X, Y);    // X=[Xq0,Yq0,Xq2,Yq2]        Y=[Xq1,Yq1,Xq3,Yq3]
    pl16s(Xp, Yp);  // same for nt1
    pl32s(X, Xp);   // X=[Xq0,Yq0,X'q0,Y'q0]      Xp=[Xq2,Yq2,X'q2,Y'q2]
    pl32s(Y, Yp);   // Y=[Xq1,Yq1,X'q1,Y'q1]      Yp=[Xq3,Yq3,X'q3,Y'q3]
    pl16s(X, Xp);   // X=pu0=[Xq0,Xq2,X'q0,X'q2]  Xp=pu1=[Yq0,Yq2,Y'q0,Y'q2]
    pl16s(Y, Yp);   // Y=pu2=[Xq1,Xq3,X'q1,X'q3]  Yp=pu3=[Yq1,Yq3,Y'q1,Y'q3]
    // junk (kw 12-15, q3-sourced) sits in pu2/pu3 at odd quads -> zero
    union { u32x4 u; bf16x8 v; } pu;
    pu.u[0] = X;
    pu.u[1] = Xp;
    pu.u[2] = (quad & 1) ? 0u : Y;
    pu.u[3] = (quad & 1) ? 0u : Yp;
    bf16x8 vb = *(const bf16x8*)&v_lds[col][ks * 32 + quad * 8];
    oacc = mfma16(pu.v, vb, oacc);
    oaccS = mfma16(pu.v, ones, oaccS);
  }
  for (int r4 = 0; r4 < 4; ++r4) {
    int qg = wave * 16 + quad * 4 + r4;
    int qy = qg >> 3, qx = qg & 7;
    float val = oacc[r4] * __builtin_amdgcn_rcpf(oaccS[r4]);
    ao[(long)head * 2097152 +
       (pb + (wy * 8 + qy) * 256 + wx * 8 + qx) * 16 + col] = f2b(val);
  }
}

// ---------------------------------------------------------------------------
// Kernel 3: proj 1x1 conv.  LDS-free.  Grid (512, 2) x 4 waves; wave = 64
// px; blockIdx.y selects mt range [3y, 3y+3) (disjoint output channels).
// A = pre-split weights (prefetched), B = ao pixels (b128 loads from
// head-major planes), C row = output channel -> f32 planar stores.
// ---------------------------------------------------------------------------
__global__ __launch_bounds__(256) void proj_kernel(
    const short* __restrict__ ao, const short* __restrict__ pwh,
    const short* __restrict__ pwl, const float* __restrict__ bias,
    float* __restrict__ out) {
  const int tid = threadIdx.x;
  const int wave = tid >> 6, lane = tid & 63;
  const int quad = lane >> 4, col = lane & 15;
  const int blk = blockIdx.x;  // 512 blocks
  const int b = blk >> 8;
  const int m0 = blockIdx.y * 3;  // this block's mt range: [m0, m0+3)
  const long pix0 = (long)blk * 256 + wave * 64 + col;

  bf16x8 bfr[4][3];
#pragma unroll
  for (int tile = 0; tile < 4; ++tile)
#pragma unroll
    for (int ks = 0; ks < 3; ++ks) {
      int head = 2 * ks + (quad >> 1);
      bfr[tile][ks] =
          *(const bf16x8*)(ao + (long)head * 2097152 +
                           (pix0 + tile * 16) * 16 + (quad & 1) * 8);
    }

  const short* wbh = pwh + col * 96 + quad * 8;
  const short* wbl = pwl + col * 96 + quad * 8;
  bf16x8 ah[3], al[3];
#pragma unroll
  for (int ks = 0; ks < 3; ++ks) {
    ah[ks] = *(const bf16x8*)(wbh + m0 * 1536 + ks * 32);
    al[ks] = *(const bf16x8*)(wbl + m0 * 1536 + ks * 32);
  }
  float* ob = out + (((long)(b * 96 + quad * 4)) << 16) + (blk & 255) * 256 +
              wave * 64 + col;
#pragma unroll
  for (int mm = 0; mm < 3; ++mm) {
    const int mt = m0 + mm;
    bf16x8 nh[3], nl[3];
    if (mm < 2) {
#pragma unroll
      for (int ks = 0; ks < 3; ++ks) {
        nh[ks] = *(const bf16x8*)(wbh + (mt + 1) * 1536 + ks * 32);
        nl[ks] = *(const bf16x8*)(wbl + (mt + 1) * 1536 + ks * 32);
      }
    }
    f32x4 bv = *(const f32x4*)(bias + mt * 16 + quad * 4);
    f32x4 acc[4] = {bv, bv, bv, bv};
#pragma unroll
    for (int ks = 0; ks < 3; ++ks)
#pragma unroll
      for (int tile = 0; tile < 4; ++tile) {
        acc[tile] = mfma16(ah[ks], bfr[tile][ks], acc[tile]);
        acc[tile] = mfma16(al[ks], bfr[tile][ks], acc[tile]);
      }
    float* obm = ob + ((long)(mt * 16) << 16);
#pragma unroll
    for (int tile = 0; tile < 4; ++tile)
#pragma unroll
      for (int r = 0; r < 4; ++r)
        obm[((long)r << 16) + tile * 16] = acc[tile][r];
    if (mm < 2) {
#pragma unroll
      for (int ks = 0; ks < 3; ++ks) {
        ah[ks] = nh[ks];
        al[ks] = nl[ks];
      }
    }
  }
}

extern "C" void kernel_launch(void* const* d_in, const int* in_sizes, int n_in,
                              void* d_out, int out_size, void* d_ws,
                              size_t ws_size, hipStream_t stream) {
  const float* x = (const float*)d_in[0];
  const float* qkv_w = (const float*)d_in[1];
  const float* qkv_b = (const float*)d_in[2];
  const float* proj_w = (const float*)d_in[3];
  const float* proj_b = (const float*)d_in[4];
  const float* rel_h = (const float*)d_in[5];
  const float* rel_w = (const float*)d_in[6];

  const long NPIXC = 131072L * 96L;
  short* q_t = (short*)d_ws;
  short* k_t = q_t + NPIXC;           // padded: 12 * KPLANE shorts
  short* v_t = k_t + 12 * KPLANE;
  short* ao = v_t + NPIXC;
  short* qwh = ao + NPIXC;
  short* qwl = qwh + 288 * 96;
  short* pwh = qwl + 288 * 96;
  short* pwl = pwh + 96 * 96;
  short* rhb = pwl + 96 * 96;
  short* rwb = rhb + 368;
  float* sbias = (float*)(rwb + 368);
  float* out = (float*)d_out;

  hipLaunchKernelGGL(prep_kernel, dim3(108), dim3(256), 0, stream, qkv_w,
                     proj_w, rel_h, rel_w, qkv_b, qwh, qwl, pwh, pwl, rhb, rwb,
                     sbias, k_t);
  hipLaunchKernelGGL(qkv_kernel, dim3(512, 2), dim3(256), 0, stream, x, qwh,
                     qwl, sbias, q_t, k_t, v_t);
  hipLaunchKernelGGL(attn_kernel, dim3(2048, 6), dim3(256), 0, stream, q_t,
                     k_t, v_t, rhb, rwb, ao);
  hipLaunchKernelGGL(proj_kernel, dim3(512, 2), dim3(256), 0, stream, ao, pwh,
                     pwl, proj_b, out);
}

// Round 8
// 187.233 us; speedup vs baseline: 1.0293x; 1.0293x over previous
//
#include <hip/hip_runtime.h>
#include <hip/hip_bf16.h>

// HaloNet-style windowed attention, MI355X gfx950.  f32 in / f32 out.
// bf16 MFMA internals; w hi/lo split keeps conv weights exact; x/q/k/v/P/ao
// single bf16 (absmax ~4.9e-4 vs 2.54e-3 threshold).
// ws layout (shorts):
//   q_t [head][pix][16]                    12,582,912   (scaled 0.25*log2e)
//   k_t [head*2+b][260*260 padded][16]     12,979,200   (2-px ZERO border)
//   v_t [head][pix][16]                    12,582,912
//   ao  [head][pix][16]                    12,582,912
//   weights/tables/sbias                       ~75,616
// Total ~101.6 MB.
//
// This round: attn SLOT-REMAPPED key ordering — permlane transpose deleted.
// slot(kh,kw) = (kh>>1)*32 + (kw>>2)*8 + (kh&1)*4 + (kw&3): QK-swapped
// output pairs land DIRECTLY at the PV A-frag k-positions (pu = 4 cvt_pk,
// no shuffles).  Junk kw 12-15 sits wholly in quad-3 lanes' k-slots: V
// staged zero there + ones-frag zeroed for quad 3 -> excluded from both
// numerator and denominator; Ws[q][12..15]=0 init keeps junk P finite
// (NaN*0=NaN in MFMA otherwise).  qkv/proj reverted to round-5 verified
// text (512 blocks) — non-attn has been ~137 us across 3 implementations
// (fixed harness cost), so attn is the only live lever.

typedef __attribute__((ext_vector_type(8))) short bf16x8;
typedef __attribute__((ext_vector_type(4))) float f32x4;
typedef __attribute__((ext_vector_type(4))) unsigned u32x4;

__device__ __forceinline__ f32x4 mfma16(bf16x8 a, bf16x8 b, f32x4 c) {
  // D[a_idx][b_idx] = sum_k A[a_idx][k]*B[b_idx][k]
  // A/B frag: idx=lane&15, k=(lane>>4)*8+j; D: col=lane&15 (B-idx),
  // row=(lane>>4)*4+reg (A-idx)   [learn_hip m89/m91]
  return __builtin_amdgcn_mfma_f32_16x16x32_bf16(a, b, c, 0, 0, 0);
}
// branchless RNE f32->bf16 (finite inputs only — true for this problem)
__device__ __forceinline__ short f2b(float f) {
  unsigned u = __builtin_bit_cast(unsigned, f);
  unsigned r = u + 0x7fffu + ((u >> 16) & 1u);
  return (short)(r >> 16);
}
// packed RNE pair: low16 = bf16(lo), high16 = bf16(hi)
__device__ __forceinline__ unsigned cvtpk(float lo, float hi) {
  unsigned r;
  asm("v_cvt_pk_bf16_f32 %0, %1, %2" : "=v"(r) : "v"(lo), "v"(hi));
  return r;
}
// x = hi + lo, hi = trunc-to-bf16(x) (x-hi exact), lo = RNE(residual)
__device__ __forceinline__ void splitf(float x, short& h, short& l) {
  unsigned u = __builtin_bit_cast(unsigned, x);
  h = (short)(u >> 16);
  float fh = __builtin_bit_cast(float, u & 0xffff0000u);
  l = f2b(x - fh);
}

#define KPLANE 1081600L  // 67600 px * 16 ch
#define QS (0.25f * 1.44269504f)

// ---------------------------------------------------------------------------
// Kernel 0: one-time prep — split conv weights hi/lo (q rows pre-scaled by
// 0.25*log2e), scaled bias, rel tables, zero the 2-px border of all 12
// padded K planes.  Grid 108x256 = 27648 threads covers all tasks.
// ---------------------------------------------------------------------------
__global__ __launch_bounds__(256) void prep_kernel(
    const float* __restrict__ qkv_w, const float* __restrict__ proj_w,
    const float* __restrict__ rel_h, const float* __restrict__ rel_w,
    const float* __restrict__ qkv_b,
    short* __restrict__ qwh, short* __restrict__ qwl,
    short* __restrict__ pwh, short* __restrict__ pwl,
    short* __restrict__ rhb, short* __restrict__ rwb,
    float* __restrict__ sbias, short* __restrict__ k_t) {
  int i = blockIdx.x * 256 + threadIdx.x;
  if (i < 288 * 96) {
    float wv = qkv_w[i];
    if (i < 96 * 96) wv *= QS;  // q rows pre-scaled
    short h, l;
    splitf(wv, h, l);
    qwh[i] = h;
    qwl[i] = l;
  }
  if (i < 96 * 96) {
    short h, l;
    splitf(proj_w[i], h, l);
    pwh[i] = h;
    pwl[i] = l;
  }
  if (i < 368) {
    rhb[i] = f2b(rel_h[i]);
    rwb[i] = f2b(rel_w[i]);
  }
  if (i < 288) sbias[i] = qkv_b[i] * (i < 96 ? QS : 1.0f);
  if (i < 12 * 2064) {  // border pixels: rows {0,1,258,259} + cols {0,1,258,259}
    int plane = i / 2064, r = i - plane * 2064;
    int py, px;
    if (r < 1040) {
      int rowid = r / 260;
      py = (rowid < 2) ? rowid : 256 + rowid;
      px = r - rowid * 260;
    } else {
      int r2 = r - 1040;
      py = 2 + (r2 >> 2);
      int cid = r2 & 3;
      px = (cid < 2) ? cid : 256 + cid;
    }
    bf16x8 z = {0, 0, 0, 0, 0, 0, 0, 0};
    long base = (long)plane * KPLANE + (long)(py * 260 + px) * 16;
    *(bf16x8*)(k_t + base) = z;
    *(bf16x8*)(k_t + base + 8) = z;
  }
}

// ---------------------------------------------------------------------------
// Kernel 1: QKV 1x1 conv.  LDS-free.  512 blocks x 4 waves; wave = 64 px.
// B-frag (pixels) direct from planar f32; A = pre-split weights, prefetched
// one t6 ahead.  C row = output channel -> cvt_pk + dword stores.
// (round-5 verified text)
// ---------------------------------------------------------------------------
__global__ __launch_bounds__(256) void qkv_kernel(
    const float* __restrict__ x, const short* __restrict__ qwh,
    const short* __restrict__ qwl, const float* __restrict__ sbias,
    short* __restrict__ q_t, short* __restrict__ k_t,
    short* __restrict__ v_t) {
  const int tid = threadIdx.x;
  const int wave = tid >> 6, lane = tid & 63;
  const int quad = lane >> 4, col = lane & 15;
  const int blk = blockIdx.x;        // 512 blocks = 2 images x 256 rows
  const int b = blk >> 8, row = blk & 255;

  // ---- B fragments: x[ch][pix] -> bf16, pixel=col, k=quad*8+j
  const float* xw = x + (((long)b * 96) << 16) + row * 256 + wave * 64 + col;
  bf16x8 bx[4][3];
#pragma unroll
  for (int tile = 0; tile < 4; ++tile)
#pragma unroll
    for (int ks = 0; ks < 3; ++ks) {
      const float* p = xw + tile * 16 + (((long)(ks * 32 + quad * 8)) << 16);
      float v0 = p[0];
      float v1 = p[1L << 16];
      float v2 = p[2L << 16];
      float v3 = p[3L << 16];
      float v4 = p[4L << 16];
      float v5 = p[5L << 16];
      float v6 = p[6L << 16];
      float v7 = p[7L << 16];
      union { unsigned u[4]; bf16x8 w; } t;
      t.u[0] = cvtpk(v0, v1);
      t.u[1] = cvtpk(v2, v3);
      t.u[2] = cvtpk(v4, v5);
      t.u[3] = cvtpk(v6, v7);
      bx[tile][ks] = t.w;
    }

  // ---- weight fragments (A): row = output = base+col
  const short* wbh = qwh + col * 96 + quad * 8;
  const short* wbl = qwl + col * 96 + quad * 8;
  bf16x8 wh[3], wl[3];
#pragma unroll
  for (int ks = 0; ks < 3; ++ks) {
    wh[ks] = *(const bf16x8*)(wbh + ks * 32);
    wl[ks] = *(const bf16x8*)(wbl + ks * 32);
  }

  const long pixb = (long)blk * 256 + wave * 64 + col;  // tile0 pixel
  short* kbase = k_t + (long)b * KPLANE +
                 ((long)((row + 2) * 260 + wave * 64 + col + 2)) * 16 +
                 quad * 4;

#pragma unroll
  for (int t6 = 0; t6 < 18; ++t6) {
    bf16x8 nh[3], nl[3];
    if (t6 < 17) {
#pragma unroll
      for (int ks = 0; ks < 3; ++ks) {
        nh[ks] = *(const bf16x8*)(wbh + (t6 + 1) * 1536 + ks * 32);
        nl[ks] = *(const bf16x8*)(wbl + (t6 + 1) * 1536 + ks * 32);
      }
    }
    f32x4 bv = *(const f32x4*)(sbias + t6 * 16 + quad * 4);
    f32x4 acc[4] = {bv, bv, bv, bv};
#pragma unroll
    for (int ks = 0; ks < 3; ++ks)
#pragma unroll
      for (int tile = 0; tile < 4; ++tile) {
        acc[tile] = mfma16(wh[ks], bx[tile][ks], acc[tile]);
        acc[tile] = mfma16(wl[ks], bx[tile][ks], acc[tile]);
      }
#pragma unroll
    for (int tile = 0; tile < 4; ++tile) {
      unsigned d0 = cvtpk(acc[tile][0], acc[tile][1]);  // ch quad*4+0,1
      unsigned d1 = cvtpk(acc[tile][2], acc[tile][3]);  // ch quad*4+2,3
      if (t6 >= 6 && t6 < 12) {  // k: padded planes [head*2+b]
        short* kp = kbase + (long)(t6 - 6) * (2 * KPLANE) + tile * 256;
        *(unsigned*)kp = d0;
        *(unsigned*)(kp + 2) = d1;
      } else {  // q/v: head-major [head][pix][16]
        short* plane = (t6 < 6 ? q_t : v_t) +
                       (long)(t6 < 6 ? t6 : t6 - 12) * 2097152 + pixb * 16 +
                       tile * 256 + quad * 4;
        *(unsigned*)plane = d0;
        *(unsigned*)(plane + 2) = d1;
      }
    }
    if (t6 < 17) {
#pragma unroll
      for (int ks = 0; ks < 3; ++ks) {
        wh[ks] = nh[ks];
        wl[ks] = nl[ks];
      }
    }
  }
}

// ---------------------------------------------------------------------------
// Kernel 2: windowed attention.  One block per (window, head); 4 waves = 4
// query tiles; one barrier (V staging).  SWAPPED QK^T: L = mfma(kf, qf)
// -> query in lanes (col), keys in regs (kw = quad*4+r4, kh = nt).
// SLOT-REMAPPED key order: slot(kh,kw) = (kh>>1)*32+(kw>>2)*8+(kh&1)*4+
// (kw&3).  PV tile ks covers slots ks*32..+31; lane (quad,q) supplies
// A[q][k=quad*8+j] = {L0[0..3],L1[0..3]} -> pu = 4 cvt_pk, NO shuffles.
// Junk kw 12-15 = quad-3 k-slots: V staged 0 there (numerator) and ones-
// frag zeroed for quad 3 (denominator); Ws[q][12..15]=0 init keeps junk P
// finite (MFMA NaN*0=NaN hazard).  OOB keys: K=0 -> logit=bias; V slot 0;
// exp2(bias) enters denominator == ref.
// ---------------------------------------------------------------------------
__global__ __launch_bounds__(256, 8) void attn_kernel(
    const short* __restrict__ q_t, const short* __restrict__ k_t,
    const short* __restrict__ v_t, const short* __restrict__ rhb,
    const short* __restrict__ rwb, short* __restrict__ ao) {
  __shared__ __attribute__((aligned(16))) short v_lds[16][210];
  __shared__ __attribute__((aligned(16))) float Wt[4][16][20];
  __shared__ __attribute__((aligned(16))) float Htab[4][16][20];

  const int orig = blockIdx.x, head = blockIdx.y;
  const int win = ((orig & 7) << 8) | (orig >> 3);  // XCD-chunked swizzle
  const int b = win >> 10, wy = (win & 1023) >> 5, wx = win & 31;
  const int y0 = wy * 8 - 2, x0 = wx * 8 - 2;
  const long pb = (long)b << 16;
  const int tid = threadIdx.x;

  // stage V transposed: v_lds[dh][slot], slot-remapped key order; OOB +
  // junk kw (12-15) zeroed.  Decode: m=slot>>5, r=slot&31 ->
  // kh = 2m + ((r>>2)&1), kw = (r>>3)*4 + (r&3).
  if (tid < 192) {
    const int m = tid >> 5, r = tid & 31;
    const int kh = m * 2 + ((r >> 2) & 1);
    const int kw = (r >> 3) * 4 + (r & 3);
    const int gy = y0 + kh, gx = x0 + kw;
    const bool valid =
        (kw < 12) && ((unsigned)gy < 256u) && ((unsigned)gx < 256u);
    if (valid) {
      const short* src =
          v_t + (long)head * 2097152 + (pb + gy * 256 + gx) * 16;
      union { bf16x8 v; short s[8]; } u0, u1;
      u0.v = *(const bf16x8*)src;
      u1.v = *(const bf16x8*)(src + 8);
      for (int d = 0; d < 8; ++d) {
        v_lds[d][tid] = u0.s[d];
        v_lds[d + 8][tid] = u1.s[d];
      }
    } else {
      for (int d = 0; d < 16; ++d) v_lds[d][tid] = 0;
    }
  }
  __syncthreads();

  const int wave = tid >> 6, lane = tid & 63;
  const int quad = lane >> 4, col = lane & 15;
  float* Ws = &Wt[wave][0][0];    // [16][20]: Wbias[q][kw]
  float* Ht = &Htab[wave][0][0];  // [16][20]: Hbias[q][kh]

  const short* qp = q_t + (long)head * 2097152;
  const short* kpb = k_t + (long)(head * 2 + b) * KPLANE;

  // Q fragment (B operand: idx=col=query; K padded 16->32: quads 2,3 zero)
  bf16x8 qf = {0, 0, 0, 0, 0, 0, 0, 0};
  if (quad < 2) {
    int qg = wave * 16 + col;
    int qy = qg >> 3, qx = qg & 7;
    qf = *(const bf16x8*)(qp + (pb + (wy * 8 + qy) * 256 + wx * 8 + qx) * 16 +
                          quad * 8);
  }

  // rel-pos dot tables, stored pre-shifted: Ws[q][kw] = wdot[q][kw-qx+11],
  // Ht[q][kh] = hdot[q][kh-qy+11].  Producer lane (col=r, quad) reg r4
  // holds dot(q=quad*4+r4, rel[r]).
  for (int nt2 = 0; nt2 < 2; ++nt2) {
    int r = nt2 * 16 + col;
    bf16x8 bw = {0, 0, 0, 0, 0, 0, 0, 0}, bh2 = bw;
    if (quad < 2 && r < 23) {
      bw = *(const bf16x8*)(rwb + r * 16 + quad * 8);
      bh2 = *(const bf16x8*)(rhb + r * 16 + quad * 8);
    }
    f32x4 z = {0.f, 0.f, 0.f, 0.f};
    f32x4 aw = mfma16(qf, bw, z);
    f32x4 ahh = mfma16(qf, bh2, z);
    int kh = r - 11 + wave * 2 + (quad >> 1);  // r4-invariant (qy = q>>3)
#pragma unroll
    for (int r4 = 0; r4 < 4; ++r4) {
      int q = quad * 4 + r4;
      int kw = r - 11 + (q & 7);
      if ((unsigned)kw < 12u) Ws[q * 20 + kw] = aw[r4];
      if ((unsigned)kh < 12u) Ht[q * 20 + kh] = ahh[r4];
    }
  }
  // junk W-bias slots kw 12..15: FINITE init (0) — quad-3 P is discarded
  // via zero-V/zero-ones, but MFMA NaN*0=NaN would still poison D.
  Ws[(lane >> 2) * 20 + 12 + (lane & 3)] = 0.0f;
  asm volatile("" ::: "memory");

  // preload biases for q=col (read once; tables dead afterwards)
  const f32x4 wv4 = *(const f32x4*)&Ws[col * 20 + quad * 4];  // kw=quad*4+r4
  const f32x4 h0 = *(const f32x4*)&Ht[col * 20];
  const f32x4 h1 = *(const f32x4*)&Ht[col * 20 + 4];
  const f32x4 h2 = *(const f32x4*)&Ht[col * 20 + 8];

  // QK^T (swapped) + bias-in-C + exp2 + direct pack + PV.
  // Pair (nt0=2ks, nt1=2ks+1): kh=nt, kw=quad*4+r4 in regs.
  const short* kb =
      kpb + (long)((wy * 8) * 260 + wx * 8 + col) * 16 + quad * 8;
  const bf16x8 ones = {0x3F80, 0x3F80, 0x3F80, 0x3F80,
                       0x3F80, 0x3F80, 0x3F80, 0x3F80};
  const bf16x8 zero8 = {0, 0, 0, 0, 0, 0, 0, 0};
  const bf16x8 onesv = (quad < 3) ? ones : zero8;  // junk k-slots excluded
  f32x4 oacc = {0.f, 0.f, 0.f, 0.f}, oaccS = oacc;
#pragma unroll
  for (int ks = 0; ks < 6; ++ks) {
    const int nt0 = 2 * ks, nt1 = 2 * ks + 1;
    bf16x8 kf0 = *(const bf16x8*)(kb + (long)nt0 * 4160);
    bf16x8 kf1 = *(const bf16x8*)(kb + (long)nt1 * 4160);
    float hs0 = nt0 < 4 ? h0[nt0] : (nt0 < 8 ? h1[nt0 - 4] : h2[nt0 - 8]);
    float hs1 = nt1 < 4 ? h0[nt1] : (nt1 < 8 ? h1[nt1 - 4] : h2[nt1 - 8]);
    f32x4 a0 = wv4 + hs0, a1 = wv4 + hs1;
    f32x4 L0 = mfma16(kf0, qf, a0);  // row=kw=quad*4+r4, col=q
    f32x4 L1 = mfma16(kf1, qf, a1);
    // A[q=col][k=quad*8+j]: j=0..3 <- L0 (kh=nt0), j=4..7 <- L1 (kh=nt1);
    // slot(kh,kw) puts lane's own values exactly here — no shuffles.
    union { u32x4 u; bf16x8 v; } pu;
    pu.u[0] = cvtpk(__builtin_amdgcn_exp2f(L0[0]),
                    __builtin_amdgcn_exp2f(L0[1]));
    pu.u[1] = cvtpk(__builtin_amdgcn_exp2f(L0[2]),
                    __builtin_amdgcn_exp2f(L0[3]));
    pu.u[2] = cvtpk(__builtin_amdgcn_exp2f(L1[0]),
                    __builtin_amdgcn_exp2f(L1[1]));
    pu.u[3] = cvtpk(__builtin_amdgcn_exp2f(L1[2]),
                    __builtin_amdgcn_exp2f(L1[3]));
    bf16x8 vb = *(const bf16x8*)&v_lds[col][ks * 32 + quad * 8];
    oacc = mfma16(pu.v, vb, oacc);
    oaccS = mfma16(pu.v, onesv, oaccS);
  }
  for (int r4 = 0; r4 < 4; ++r4) {
    int qg = wave * 16 + quad * 4 + r4;
    int qy = qg >> 3, qx = qg & 7;
    float val = oacc[r4] * __builtin_amdgcn_rcpf(oaccS[r4]);
    ao[(long)head * 2097152 +
       (pb + (wy * 8 + qy) * 256 + wx * 8 + qx) * 16 + col] = f2b(val);
  }
}

// ---------------------------------------------------------------------------
// Kernel 3: proj 1x1 conv.  LDS-free.  512 blocks x 4 waves; wave = 64 px.
// A = pre-split weights (prefetched), B = ao pixels (b128 loads from
// head-major planes), C row = output channel -> f32 planar stores.
// (round-5 verified text)
// ---------------------------------------------------------------------------
__global__ __launch_bounds__(256) void proj_kernel(
    const short* __restrict__ ao, const short* __restrict__ pwh,
    const short* __restrict__ pwl, const float* __restrict__ bias,
    float* __restrict__ out) {
  const int tid = threadIdx.x;
  const int wave = tid >> 6, lane = tid & 63;
  const int quad = lane >> 4, col = lane & 15;
  const int blk = blockIdx.x;  // 512 blocks
  const int b = blk >> 8;
  const long pix0 = (long)blk * 256 + wave * 64 + col;

  bf16x8 bfr[4][3];
#pragma unroll
  for (int tile = 0; tile < 4; ++tile)
#pragma unroll
    for (int ks = 0; ks < 3; ++ks) {
      int head = 2 * ks + (quad >> 1);
      bfr[tile][ks] =
          *(const bf16x8*)(ao + (long)head * 2097152 +
                           (pix0 + tile * 16) * 16 + (quad & 1) * 8);
    }

  const short* wbh = pwh + col * 96 + quad * 8;
  const short* wbl = pwl + col * 96 + quad * 8;
  bf16x8 ah[3], al[3];
#pragma unroll
  for (int ks = 0; ks < 3; ++ks) {
    ah[ks] = *(const bf16x8*)(wbh + ks * 32);
    al[ks] = *(const bf16x8*)(wbl + ks * 32);
  }
  float* ob = out + (((long)(b * 96 + quad * 4)) << 16) + (blk & 255) * 256 +
              wave * 64 + col;
#pragma unroll
  for (int mt = 0; mt < 6; ++mt) {
    bf16x8 nh[3], nl[3];
    if (mt < 5) {
#pragma unroll
      for (int ks = 0; ks < 3; ++ks) {
        nh[ks] = *(const bf16x8*)(wbh + (mt + 1) * 1536 + ks * 32);
        nl[ks] = *(const bf16x8*)(wbl + (mt + 1) * 1536 + ks * 32);
      }
    }
    f32x4 bv = *(const f32x4*)(bias + mt * 16 + quad * 4);
    f32x4 acc[4] = {bv, bv, bv, bv};
#pragma unroll
    for (int ks = 0; ks < 3; ++ks)
#pragma unroll
      for (int tile = 0; tile < 4; ++tile) {
        acc[tile] = mfma16(ah[ks], bfr[tile][ks], acc[tile]);
        acc[tile] = mfma16(al[ks], bfr[tile][ks], acc[tile]);
      }
    float* obm = ob + ((long)(mt * 16) << 16);
#pragma unroll
    for (int tile = 0; tile < 4; ++tile)
#pragma unroll
      for (int r = 0; r < 4; ++r)
        obm[((long)r << 16) + tile * 16] = acc[tile][r];
    if (mt < 5) {
#pragma unroll
      for (int ks = 0; ks < 3; ++ks) {
        ah[ks] = nh[ks];
        al[ks] = nl[ks];
      }
    }
  }
}

extern "C" void kernel_launch(void* const* d_in, const int* in_sizes, int n_in,
                              void* d_out, int out_size, void* d_ws,
                              size_t ws_size, hipStream_t stream) {
  const float* x = (const float*)d_in[0];
  const float* qkv_w = (const float*)d_in[1];
  const float* qkv_b = (const float*)d_in[2];
  const float* proj_w = (const float*)d_in[3];
  const float* proj_b = (const float*)d_in[4];
  const float* rel_h = (const float*)d_in[5];
  const float* rel_w = (const float*)d_in[6];

  const long NPIXC = 131072L * 96L;
  short* q_t = (short*)d_ws;
  short* k_t = q_t + NPIXC;           // padded: 12 * KPLANE shorts
  short* v_t = k_t + 12 * KPLANE;
  short* ao = v_t + NPIXC;
  short* qwh = ao + NPIXC;
  short* qwl = qwh + 288 * 96;
  short* pwh = qwl + 288 * 96;
  short* pwl = pwh + 96 * 96;
  short* rhb = pwl + 96 * 96;
  short* rwb = rhb + 368;
  float* sbias = (float*)(rwb + 368);
  float* out = (float*)d_out;

  hipLaunchKernelGGL(prep_kernel, dim3(108), dim3(256), 0, stream, qkv_w,
                     proj_w, rel_h, rel_w, qkv_b, qwh, qwl, pwh, pwl, rhb, rwb,
                     sbias, k_t);
  hipLaunchKernelGGL(qkv_kernel, dim3(512), dim3(256), 0, stream, x, qwh, qwl,
                     sbias, q_t, k_t, v_t);
  hipLaunchKernelGGL(attn_kernel, dim3(2048, 6), dim3(256), 0, stream, q_t,
                     k_t, v_t, rhb, rwb, ao);
  hipLaunchKernelGGL(proj_kernel, dim3(512), dim3(256), 0, stream, ao, pwh,
                     pwl, proj_b, out);
}